// Round 18
// baseline (458.764 us; speedup 1.0000x reference)
//
#include <hip/hip_runtime.h>

#define NND 100000
#define NED 1600000
#define NB  1024
#define FEAT 9
#define HC 128
#define NBUCK ((NND + 511) / 512)            // 196 buckets of 512 nodes
#define BCAP 12288u                          // fixed bucket capacity (mean 8192, +45 sigma)
#define BINCHUNK 4096
#define BIN_NBLK ((NED + BINCHUNK - 1) / BINCHUNK)  // 391

typedef unsigned short u16;

__device__ __forceinline__ void atomAdd(float* p, float v) {
    __hip_atomic_fetch_add(p, v, __ATOMIC_RELAXED, __HIP_MEMORY_SCOPE_AGENT);
}
__device__ __forceinline__ unsigned atomAddU(unsigned* p, unsigned v) {
    return __hip_atomic_fetch_add(p, v, __ATOMIC_RELAXED, __HIP_MEMORY_SCOPE_AGENT);
}
__device__ __forceinline__ float leaky(float v, float s) { return v >= 0.f ? v : s * v; }
__device__ __forceinline__ float bf2f(u16 u) {
    union { unsigned i; float f; } x; x.i = ((unsigned)u) << 16; return x.f;
}
__device__ __forceinline__ u16 f2bf(float f) {
    union { float f; unsigned i; } x; x.f = f;
    return (u16)((x.i + 0x7fffu + ((x.i >> 16) & 1u)) >> 16);
}
__device__ __forceinline__ float bflo(unsigned u) {
    union { unsigned i; float f; } x; x.i = u << 16; return x.f;
}
__device__ __forceinline__ float bfhi(unsigned u) {
    union { unsigned i; float f; } x; x.i = u & 0xffff0000u; return x.f;
}

typedef __attribute__((ext_vector_type(8))) short bfrag;
typedef __attribute__((ext_vector_type(4))) float ffrag;

// ---- K1: M tables + BN scale/offset folding (one block, 128 thr) ----
__global__ void k_matt(const float* __restrict__ Wg, const float* __restrict__ attS,
                       const float* __restrict__ attD,
                       const float* __restrict__ c1b, const float* __restrict__ c2b,
                       const float* __restrict__ g1n, const float* __restrict__ b1n,
                       const float* __restrict__ m1n, const float* __restrict__ v1n,
                       const float* __restrict__ g2n, const float* __restrict__ b2n,
                       const float* __restrict__ m2n, const float* __restrict__ v2n,
                       float* __restrict__ M, float* __restrict__ scv) {
    int t = threadIdx.x;  // 128
    if (t < 64) {
        float s1 = g1n[t] * rsqrtf(v1n[t] + 1e-5f);
        float s2 = g2n[t] * rsqrtf(v2n[t] + 1e-5f);
        scv[t] = s1;
        scv[64 + t] = (c1b[t] - m1n[t]) * s1 + b1n[t];
        scv[128 + t] = s2;
        scv[192 + t] = (c2b[t] - m2n[t]) * s2 + b2n[t];
    }
    if (t >= 72) return;
    int d = t >= 36 ? 1 : 0;
    int q = t - 36 * d;
    int f = q >> 2, h = q & 3;
    const float* av = d ? attD : attS;
    float s = 0.f;
#pragma unroll
    for (int c = 0; c < 32; ++c) s += Wg[f * HC + h * 32 + c] * av[h * 32 + c];
    M[d * 36 + q] = s;
}

// ---- K1b: weight tables; w1p padded [64][96]; w2c [64][192]; init bktCur ----
__global__ void k_w2t(const float* __restrict__ W2, const float* __restrict__ W3,
                      const float* __restrict__ Wg,
                      const float* __restrict__ c1w, const float* __restrict__ c2w,
                      u16* __restrict__ w2t, u16* __restrict__ w3t,
                      u16* __restrict__ wgt, u16* __restrict__ w1p,
                      u16* __restrict__ w2c, unsigned* __restrict__ bktCur) {
    int i = blockIdx.x * 256 + threadIdx.x;  // 8192
    int n = i >> 7, k = i & 127;
    w2t[i] = f2bf(W2[k * 64 + n]);
    int n3 = i >> 6, k3 = i & 63;
    w3t[i] = f2bf(W3[k3 * 128 + n3]);
    int col = i >> 6, kk = i & 63;
    int f = kk - 9 * (col >> 5);
    wgt[i] = (f >= 0 && f < 9) ? f2bf(Wg[f * 128 + col]) : (u16)0;
    if (i < 6144) {
        int o = i / 96, kw = i - o * 96;
        w1p[i] = (kw < 90) ? f2bf(c1w[o * 90 + kw]) : (u16)0;
    }
    for (int j = i; j < 12288; j += 8192) w2c[j] = f2bf(c2w[j]);
    if (i < NBUCK) bktCur[i] = (unsigned)i * BCAP;
}

// ---- K2: per-node 32B bf16 record rec = {x[9], pad[3], a_s[4]} + a_d f32 ----
__global__ void k_att(const float* __restrict__ x, const float* __restrict__ M,
                      u16* __restrict__ rec, float* __restrict__ a_d) {
    __shared__ float Ms[36], Md[36];
    int t = threadIdx.x;  // 256
    if (t < 36) Ms[t] = M[t];
    else if (t < 72) Md[t - 36] = M[t];
    __syncthreads();
    int n = blockIdx.x * 256 + t;
    if (n >= NND) return;
    float xv[FEAT];
#pragma unroll
    for (int f = 0; f < FEAT; ++f) xv[f] = x[n * FEAT + f];
    float s0 = 0, s1 = 0, s2 = 0, s3 = 0, d0 = 0, d1 = 0, d2 = 0, d3 = 0;
#pragma unroll
    for (int f = 0; f < FEAT; ++f) {
        float xf = xv[f];
        s0 += xf * Ms[f * 4 + 0]; s1 += xf * Ms[f * 4 + 1];
        s2 += xf * Ms[f * 4 + 2]; s3 += xf * Ms[f * 4 + 3];
        d0 += xf * Md[f * 4 + 0]; d1 += xf * Md[f * 4 + 1];
        d2 += xf * Md[f * 4 + 2]; d3 += xf * Md[f * 4 + 3];
    }
    u16 v[16];
#pragma unroll
    for (int f = 0; f < FEAT; ++f) v[f] = f2bf(xv[f]);
    v[9] = 0; v[10] = 0; v[11] = 0;
    v[12] = f2bf(s0); v[13] = f2bf(s1); v[14] = f2bf(s2); v[15] = f2bf(s3);
    unsigned pk[8];
#pragma unroll
    for (int i = 0; i < 8; ++i) pk[i] = (unsigned)v[2 * i] | ((unsigned)v[2 * i + 1] << 16);
    uint4* rp = (uint4*)(rec + (size_t)n * 16);
    rp[0] = make_uint4(pk[0], pk[1], pk[2], pk[3]);
    rp[1] = make_uint4(pk[4], pk[5], pk[6], pk[7]);
    ((float4*)a_d)[n] = make_float4(d0, d1, d2, d3);
}

// ---- K5: bin edges into fixed-capacity bucket staging, packed (dstLocal<<17)|src ----
__global__ __launch_bounds__(256) void k_bin(const int* __restrict__ ei,
                                             unsigned* __restrict__ bktCursor,
                                             unsigned* __restrict__ staging) {
    __shared__ unsigned hist[NBUCK];
    __shared__ unsigned gbase[NBUCK];
    int t = threadIdx.x;
    if (t < NBUCK) hist[t] = 0;
    __syncthreads();
    int base = blockIdx.x * BINCHUNK;
    int lim = NED - base;
    int srcv[16], dstv[16];
#pragma unroll
    for (int k = 0; k < 16; ++k) {
        int i = t + k * 256;
        if (i < lim) {
            srcv[k] = ei[base + i];
            dstv[k] = ei[NED + base + i];
            atomicAdd(&hist[dstv[k] >> 9], 1u);
        } else dstv[k] = -1;
    }
    __syncthreads();
    if (t < NBUCK) {
        unsigned c = hist[t];
        gbase[t] = c ? atomAddU(&bktCursor[t], c) : 0u;
    }
    __syncthreads();
    if (t < NBUCK) hist[t] = 0;
    __syncthreads();
#pragma unroll
    for (int k = 0; k < 16; ++k) {
        if (dstv[k] >= 0) {
            int bk = dstv[k] >> 9;
            unsigned off = atomicAdd(&hist[bk], 1u);
            staging[gbase[bk] + off] = ((unsigned)(dstv[k] & 511) << 17) | (unsigned)srcv[k];
        }
    }
}

// ---- K6: per-bucket CSR build ----
__global__ __launch_bounds__(512) void k_place(const unsigned* __restrict__ bktCur,
                                               const unsigned* __restrict__ staging,
                                               unsigned* __restrict__ csr,
                                               unsigned* __restrict__ rowptr,
                                               u16* __restrict__ degA,
                                               float* __restrict__ dinv) {
    __shared__ unsigned lh[512];
    __shared__ unsigned ls[512];
    int b = blockIdx.x, t = threadIdx.x;
    unsigned lo = (unsigned)b * BCAP;
    unsigned n = bktCur[b] - lo;
    lh[t] = 0;
    __syncthreads();
    for (unsigned i = t; i < n; i += 512) atomicAdd(&lh[staging[lo + i] >> 17], 1u);
    __syncthreads();
    unsigned v = lh[t];
    ls[t] = v;
    __syncthreads();
    for (int off = 1; off < 512; off <<= 1) {
        unsigned u = (t >= off) ? ls[t - off] : 0u;
        __syncthreads();
        ls[t] += u;
        __syncthreads();
    }
    unsigned excl = ls[t] - v;
    int node = b * 512 + t;
    if (node < NND) {
        rowptr[node] = lo + excl;
        degA[node] = (u16)v;
        dinv[node] = rsqrtf((float)v + 1.f);
    }
    __syncthreads();
    lh[t] = excl;  // reuse as local cursor
    __syncthreads();
    for (unsigned i = t; i < n; i += 512) {
        unsigned p = staging[lo + i];
        unsigned pos = atomicAdd(&lh[p >> 17], 1u);
        csr[lo + pos] = p & 0x1FFFFu;
    }
}

// ---- K7: GAT aggregation, EDGE-PARALLEL: wave per node; z output bf16 ----
__global__ __launch_bounds__(256) void k_gat_g(const unsigned* __restrict__ rowptr,
                                               const u16* __restrict__ degA,
                                               const unsigned* __restrict__ csr,
                                               const u16* __restrict__ rec,
                                               const float* __restrict__ a_d,
                                               u16* __restrict__ zb) {
    int n = blockIdx.x * 4 + (threadIdx.x >> 6);  // grid NND/4 x 256 exact
    int l = threadIdx.x & 63;
    int e = l >> 2;   // 0..15 edge slot
    int h = l & 3;    // head
    unsigned e0 = rowptr[n];
    int m = (int)degA[n] + 1;  // items incl self
    float adh = a_d[n * 4 + h];
    float acc0 = 0, acc1 = 0, acc2 = 0, acc3 = 0, acc4 = 0, acc5 = 0, acc6 = 0, acc7 = 0, acc8 = 0;
    float den = 0.f;
    const uint4* recp = (const uint4*)rec;
    for (int c = 0; c < m; c += 16) {
        int idx = c + e;
        bool act = idx < m;
        int src = n;
        if (act && idx > 0) src = (int)csr[e0 + idx - 1];
        uint4 lo = recp[(size_t)src * 2];
        uint4 hi = recp[(size_t)src * 2 + 1];
        unsigned pair = (h & 2) ? hi.w : hi.z;
        float asf = (h & 1) ? bfhi(pair) : bflo(pair);
        float w = __expf(leaky(asf + adh, 0.2f));
        if (!act) w = 0.f;
        den += w;
        acc0 += w * bflo(lo.x); acc1 += w * bfhi(lo.x);
        acc2 += w * bflo(lo.y); acc3 += w * bfhi(lo.y);
        acc4 += w * bflo(lo.z); acc5 += w * bfhi(lo.z);
        acc6 += w * bflo(lo.w); acc7 += w * bfhi(lo.w);
        acc8 += w * bflo(hi.x);
    }
#pragma unroll
    for (int mask = 4; mask <= 32; mask <<= 1) {
        den  += __shfl_xor(den,  mask, 64);
        acc0 += __shfl_xor(acc0, mask, 64);
        acc1 += __shfl_xor(acc1, mask, 64);
        acc2 += __shfl_xor(acc2, mask, 64);
        acc3 += __shfl_xor(acc3, mask, 64);
        acc4 += __shfl_xor(acc4, mask, 64);
        acc5 += __shfl_xor(acc5, mask, 64);
        acc6 += __shfl_xor(acc6, mask, 64);
        acc7 += __shfl_xor(acc7, mask, 64);
        acc8 += __shfl_xor(acc8, mask, 64);
    }
    if (l < 4) {  // e==0, h=l
        float inv = 1.f / (den + 1e-16f);
        u16* zp = zb + (size_t)n * 36 + h * 9;
        zp[0] = f2bf(acc0 * inv); zp[1] = f2bf(acc1 * inv); zp[2] = f2bf(acc2 * inv);
        zp[3] = f2bf(acc3 * inv); zp[4] = f2bf(acc4 * inv); zp[5] = f2bf(acc5 * inv);
        zp[6] = f2bf(acc6 * inv); zp[7] = f2bf(acc7 * inv); zp[8] = f2bf(acc8 * inv);
    }
}

// ---- K9: MFMA g1 + MFMA h2; h2 stored PLANAR (2 planes of 32 ch, 64B rows) ----
__global__ __launch_bounds__(256) void k_fused_h2(const u16* __restrict__ zb,
                                                  const u16* __restrict__ wgt,
                                                  const float* __restrict__ bgv,
                                                  const u16* __restrict__ w2t,
                                                  const float* __restrict__ dinv,
                                                  u16* __restrict__ h2) {
    __shared__ u16 zA[64 * 72];     // 9.2 KB (K padded to 64, zeroed)
    __shared__ u16 g1L[64 * 136];   // 17.4 KB
    __shared__ float bgs[HC];
    int t = threadIdx.x;
    int n0 = blockIdx.x * 64;
    int nn = NND - n0; if (nn > 64) nn = 64;
    for (int i = t; i < 64 * 36; i += 256) ((unsigned*)zA)[i] = 0u;
    if (t < HC) bgs[t] = bgv[t];
    __syncthreads();
    const unsigned* zbG = (const unsigned*)zb;  // 18 u32 per node
    for (int i = t; i < nn * 18; i += 256) {
        int r = i / 18, c = i - r * 18;
        ((unsigned*)zA)[r * 36 + c] = zbG[(size_t)(n0 + r) * 18 + c];
    }
    __syncthreads();
    int l = t & 63, wv = t >> 6;
    int mr = l & 15, quad = l >> 4;
    union U { uint4 u; bfrag v; };
    // ---- g1 = zA @ wgt^T (K=64) -> g1L bf16 ----
    {
        bfrag a[2];
#pragma unroll
        for (int ks = 0; ks < 2; ++ks) {
            U uu; uu.u = *(const uint4*)(zA + (wv * 16 + mr) * 72 + ks * 32 + quad * 8);
            a[ks] = uu.v;
        }
#pragma unroll
        for (int ct = 0; ct < 8; ++ct) {
            ffrag c = (ffrag){0.f, 0.f, 0.f, 0.f};
#pragma unroll
            for (int ks = 0; ks < 2; ++ks) {
                U ub; ub.u = *(const uint4*)(wgt + (ct * 16 + mr) * 64 + ks * 32 + quad * 8);
                c = __builtin_amdgcn_mfma_f32_16x16x32_bf16(a[ks], ub.v, c, 0, 0, 0);
            }
            int col = ct * 16 + mr;
            float bc = bgs[col];
#pragma unroll
            for (int r = 0; r < 4; ++r) {
                int row = wv * 16 + quad * 4 + r;
                g1L[row * 136 + col] = f2bf(leaky(c[r] + bc, 0.01f));
            }
        }
    }
    __syncthreads();
    // ---- h2 = g1L @ w2t, planar store ----
    {
        bfrag a[4];
#pragma unroll
        for (int ks = 0; ks < 4; ++ks) {
            U uu; uu.u = *(const uint4*)(g1L + (wv * 16 + mr) * 136 + ks * 32 + quad * 8);
            a[ks] = uu.v;
        }
        ffrag acc[4];
#pragma unroll
        for (int ct = 0; ct < 4; ++ct) acc[ct] = (ffrag){0.f, 0.f, 0.f, 0.f};
#pragma unroll
        for (int ct = 0; ct < 4; ++ct) {
#pragma unroll
            for (int ks = 0; ks < 4; ++ks) {
                U ub; ub.u = *(const uint4*)(w2t + (ct * 16 + mr) * 128 + ks * 32 + quad * 8);
                acc[ct] = __builtin_amdgcn_mfma_f32_16x16x32_bf16(a[ks], ub.v, acc[ct], 0, 0, 0);
            }
        }
        int rbase = n0 + wv * 16 + quad * 4;
        if (rbase < NND) {  // NND%4==0
            float4 d4 = *(const float4*)(dinv + rbase);
            const float dv[4] = {d4.x, d4.y, d4.z, d4.w};
#pragma unroll
            for (int ct = 0; ct < 4; ++ct) {
                int col = ct * 16 + mr;
                size_t pbase = (size_t)(col >> 5) * NND * 32 + (col & 31);
#pragma unroll
                for (int r = 0; r < 4; ++r)
                    h2[pbase + (size_t)(rbase + r) * 32] = f2bf(dv[r] * acc[ct][r]);
            }
        }
    }
}

// ---- K10/K11: GCN aggregation, PLANAR half-channel pass (32 ch, 64B rows) ----
// wave per node: 8 edges at once, 8 lanes/edge (uint2 = 4 ch each).
// OUTMODE 1: bf16(dinv*leaky(dn*acc+bias)); OUTMODE 0: bf16(dn*acc)
template <int OUTMODE>
__global__ void k_gcn_gp(const unsigned* __restrict__ rowptr, const u16* __restrict__ degA,
                         const unsigned* __restrict__ csr,
                         const float* __restrict__ dinv, const u16* __restrict__ hin,
                         const float* __restrict__ bias, u16* __restrict__ hout) {
    int n = blockIdx.x * 4 + (threadIdx.x >> 6);  // grid 25000 x 256 exact
    int l = threadIdx.x & 63;
    int grp = l >> 3;   // edge offset 0..7
    int c = l & 7;      // channel quad: channels 4c..4c+3 (within plane)
    unsigned e0 = rowptr[n];
    unsigned e1 = e0 + degA[n];
    const uint2* hinU = (const uint2*)hin;  // row = 8 uint2
    float a0 = 0, a1 = 0, a2 = 0, a3 = 0;
    if (grp == 0) {  // self term (pre-scaled at producer)
        uint2 u = hinU[(size_t)n * 8 + c];
        a0 = bflo(u.x); a1 = bfhi(u.x); a2 = bflo(u.y); a3 = bfhi(u.y);
    }
    unsigned e = e0;
    for (; e + 16 <= e1; e += 16) {
        unsigned s0 = csr[e + grp];
        unsigned s1 = csr[e + 8 + grp];
        uint2 u0 = hinU[(size_t)s0 * 8 + c];
        uint2 u1 = hinU[(size_t)s1 * 8 + c];
        a0 += bflo(u0.x) + bflo(u1.x); a1 += bfhi(u0.x) + bfhi(u1.x);
        a2 += bflo(u0.y) + bflo(u1.y); a3 += bfhi(u0.y) + bfhi(u1.y);
    }
    for (; e + 8 <= e1; e += 8) {
        unsigned s = csr[e + grp];
        uint2 u = hinU[(size_t)s * 8 + c];
        a0 += bflo(u.x); a1 += bfhi(u.x); a2 += bflo(u.y); a3 += bfhi(u.y);
    }
    if (grp < (int)(e1 - e)) {
        unsigned s = csr[e + grp];
        uint2 u = hinU[(size_t)s * 8 + c];
        a0 += bflo(u.x); a1 += bfhi(u.x); a2 += bflo(u.y); a3 += bfhi(u.y);
    }
#pragma unroll
    for (int mask = 8; mask <= 32; mask <<= 1) {
        a0 += __shfl_xor(a0, mask, 64);
        a1 += __shfl_xor(a1, mask, 64);
        a2 += __shfl_xor(a2, mask, 64);
        a3 += __shfl_xor(a3, mask, 64);
    }
    if (grp == 0) {
        float dn = dinv[n];
        float o0 = dn * a0, o1 = dn * a1, o2 = dn * a2, o3 = dn * a3;
        if (OUTMODE == 1) {
            o0 = leaky(o0 + bias[4 * c],     0.01f) * dn;
            o1 = leaky(o1 + bias[4 * c + 1], 0.01f) * dn;
            o2 = leaky(o2 + bias[4 * c + 2], 0.01f) * dn;
            o3 = leaky(o3 + bias[4 * c + 3], 0.01f) * dn;
        }
        uint2 pk;
        pk.x = (unsigned)f2bf(o0) | ((unsigned)f2bf(o1) << 16);
        pk.y = (unsigned)f2bf(o2) | ((unsigned)f2bf(o3) << 16);
        ((uint2*)hout)[(size_t)n * 8 + c] = pk;
    }
}

// ---- K12: MFMA GEMM + fused mean-pool; agg3 read PLANAR ----
__global__ __launch_bounds__(256) void k_gcn2_pool(const u16* __restrict__ agg3,
                                                   const u16* __restrict__ w3t,
                                                   const float* __restrict__ b3,
                                                   const int* __restrict__ batch,
                                                   float* __restrict__ pooled,
                                                   float* __restrict__ cnt) {
    __shared__ u16 rows[64 * 72];
    __shared__ int bts[64];
    __shared__ float b3s[128];
    int t = threadIdx.x;
    int n0 = blockIdx.x * 64;
    int nn = NND - n0; if (nn > 64) nn = 64;
    for (int i = t; i < 512; i += 256) {
        int r = i >> 3, c8 = i & 7;
        uint4 v = make_uint4(0u, 0u, 0u, 0u);
        if (r < nn) {
            size_t pbase = (size_t)(c8 >> 2) * NND * 32 + (size_t)(n0 + r) * 32 + (c8 & 3) * 8;
            v = *(const uint4*)(agg3 + pbase);
        }
        *(uint4*)(rows + r * 72 + c8 * 8) = v;
    }
    if (t < 64) bts[t] = (t < nn) ? batch[n0 + t] : -1;
    if (t < 128) b3s[t] = b3[t];
    __syncthreads();
    int l = t & 63, wv = t >> 6;
    int mr = l & 15, quad = l >> 4;
    union U { uint4 u; bfrag v; };
    bfrag a[2];
#pragma unroll
    for (int ks = 0; ks < 2; ++ks) {
        U uu; uu.u = *(const uint4*)(rows + (wv * 16 + mr) * 72 + ks * 32 + quad * 8);
        a[ks] = uu.v;
    }
    ffrag acc[8];
#pragma unroll
    for (int ct = 0; ct < 8; ++ct) acc[ct] = (ffrag){0.f, 0.f, 0.f, 0.f};
#pragma unroll
    for (int ct = 0; ct < 8; ++ct) {
#pragma unroll
        for (int ks = 0; ks < 2; ++ks) {
            U ub; ub.u = *(const uint4*)(w3t + (ct * 16 + mr) * 64 + ks * 32 + quad * 8);
            acc[ct] = __builtin_amdgcn_mfma_f32_16x16x32_bf16(a[ks], ub.v, acc[ct], 0, 0, 0);
        }
    }
    int rl = wv * 16 + quad * 4;
    int ub = bts[wv * 16];
    bool uni = (ub == bts[wv * 16 + 15]);
#pragma unroll
    for (int ct = 0; ct < 8; ++ct) {
        int col = ct * 16 + mr;
        float bc = b3s[col];
        float g0 = leaky(acc[ct][0] + bc, 0.01f);
        float g1 = leaky(acc[ct][1] + bc, 0.01f);
        float g2 = leaky(acc[ct][2] + bc, 0.01f);
        float g3 = leaky(acc[ct][3] + bc, 0.01f);
        if (uni) {
            float s = g0 + g1 + g2 + g3;
            s += __shfl_xor(s, 16, 64);
            s += __shfl_xor(s, 32, 64);
            if (quad == 0 && ub >= 0) atomAdd(&pooled[ub * 128 + col], s);
        } else {
            float gr[4] = {g0, g1, g2, g3};
            int curb = bts[rl];
            float s = 0.f;
#pragma unroll
            for (int r = 0; r < 4; ++r) {
                int b = bts[rl + r];
                if (b != curb) {
                    if (curb >= 0) atomAdd(&pooled[curb * 128 + col], s);
                    s = 0.f; curb = b;
                }
                s += gr[r];
            }
            if (curb >= 0) atomAdd(&pooled[curb * 128 + col], s);
        }
    }
    if (t < nn) {
        int b = bts[t];
        if (t == 0 || bts[t - 1] != b) {
            int len = 1;
            for (int j = t + 1; j < nn && bts[j] == b; ++j) ++len;
            atomAdd(&cnt[b], (float)len);
        }
    }
}

// ---- K14: sequence branch via MFMA im2col convs -> sfc [B,64] ----
__global__ __launch_bounds__(256) void k_seq(const float* __restrict__ seq,
                      const u16* __restrict__ w1p, const u16* __restrict__ w2c,
                      const float* __restrict__ scv,
                      const float* __restrict__ fcW, const float* __restrict__ fcb,
                      float* __restrict__ sfc) {
    __shared__ float xs[600];
    __shared__ u16 A1[32 * 104];    // 6.7 KB, K padded 90->96
    __shared__ u16 y1s[64 * 20];    // [ch][l] bf16
    __shared__ u16 A2[16 * 200];    // 6.4 KB, K=192
    __shared__ float y2s[64 * 16];  // [ch][l] f32
    __shared__ float red[4][64];
    int t = threadIdx.x;  // 256
    int b = blockIdx.x;
    for (int i = t; i < 600; i += 256) xs[i] = seq[b * 600 + i];
    for (int i = t; i < 1664; i += 256) ((unsigned*)A1)[i] = 0u;
    for (int i = t; i < 1600; i += 256) ((unsigned*)A2)[i] = 0u;
    __syncthreads();
    for (int i = t; i < 18 * 90; i += 256) {
        int l = i / 90, k = i - l * 90;
        int ch = k / 3, kk = k - ch * 3;
        A1[l * 104 + k] = f2bf(xs[ch * 20 + l + kk]);
    }
    __syncthreads();
    int l = t & 63, wv = t >> 6;
    int mr = l & 15, quad = l >> 4;
    union U { uint4 u; bfrag v; };
    for (int j = wv; j < 8; j += 4) {
        int rt = j >> 2, ct = j & 3;
        ffrag c = (ffrag){0.f, 0.f, 0.f, 0.f};
#pragma unroll
        for (int ks = 0; ks < 3; ++ks) {
            U ua; ua.u = *(const uint4*)(A1 + (rt * 16 + mr) * 104 + ks * 32 + quad * 8);
            U ub; ub.u = *(const uint4*)(w1p + (ct * 16 + mr) * 96 + ks * 32 + quad * 8);
            c = __builtin_amdgcn_mfma_f32_16x16x32_bf16(ua.v, ub.v, c, 0, 0, 0);
        }
        int col = ct * 16 + mr;
        float s1 = scv[col], o1 = scv[64 + col];
#pragma unroll
        for (int r = 0; r < 4; ++r) {
            int row = rt * 16 + quad * 4 + r;
            if (row < 18) y1s[col * 20 + row] = f2bf(leaky(c[r] * s1 + o1, 0.01f));
        }
    }
    __syncthreads();
    for (int i = t; i < 16 * 192; i += 256) {
        int ll = i / 192, k = i - ll * 192;
        int ch = k / 3, kk = k - ch * 3;
        A2[ll * 200 + k] = y1s[ch * 20 + ll + kk];
    }
    __syncthreads();
    {
        int ct = wv;
        ffrag c = (ffrag){0.f, 0.f, 0.f, 0.f};
#pragma unroll
        for (int ks = 0; ks < 6; ++ks) {
            U ua; ua.u = *(const uint4*)(A2 + mr * 200 + ks * 32 + quad * 8);
            U ub; ub.u = *(const uint4*)(w2c + (ct * 16 + mr) * 192 + ks * 32 + quad * 8);
            c = __builtin_amdgcn_mfma_f32_16x16x32_bf16(ua.v, ub.v, c, 0, 0, 0);
        }
        int col = ct * 16 + mr;
        float s2 = scv[128 + col], o2 = scv[192 + col];
#pragma unroll
        for (int r = 0; r < 4; ++r) {
            int row = quad * 4 + r;
            y2s[col * 16 + row] = leaky(c[r] * s2 + o2, 0.01f);
        }
    }
    __syncthreads();
    {
        int o = t & 63, part = t >> 6;
        float acc = 0.f;
        for (int j = part * 256; j < part * 256 + 256; ++j)
            acc += y2s[j] * fcW[j * 64 + o];
        red[part][o] = acc;
    }
    __syncthreads();
    if (t < 64) sfc[b * 64 + t] = red[0][t] + red[1][t] + red[2][t] + red[3][t] + fcb[t];
}

// ---- K15: fusion + classifier -> out [B,1] f32 ----
__global__ void k_final(const float* __restrict__ pooled, const float* __restrict__ cnt,
                        const float* __restrict__ sfc,
                        const float* __restrict__ fusW, const float* __restrict__ fusb,
                        const float* __restrict__ c1W, const float* __restrict__ c1b,
                        const float* __restrict__ c3W, const float* __restrict__ c3b,
                        float* __restrict__ out) {
    __shared__ float comb[192];
    __shared__ float t1[128];
    int t = threadIdx.x;  // 128
    int b = blockIdx.x;
    float invc = 1.f / fmaxf(cnt[b], 1.f);
    comb[t] = pooled[b * 128 + t] * invc;
    if (t < 64) comb[128 + t] = sfc[b * 64 + t];
    __syncthreads();
    float acc = fusb[t];
    for (int k = 0; k < 192; ++k) acc += comb[k] * fusW[k * 128 + t];
    t1[t] = leaky(acc, 0.01f);
    __syncthreads();
    if (t < 64) {
        float a2 = c1b[t];
        for (int k = 0; k < 128; ++k) a2 += t1[k] * c1W[k * 64 + t];
        a2 = leaky(a2, 0.01f);
        float p = a2 * c3W[t];
#pragma unroll
        for (int off = 32; off; off >>= 1) p += __shfl_xor(p, off, 64);
        if (t == 0) out[b] = p + c3b[0];
    }
}

extern "C" void kernel_launch(void* const* d_in, const int* in_sizes, int n_in,
                              void* d_out, int out_size, void* d_ws, size_t ws_size,
                              hipStream_t stream) {
    const float* x     = (const float*)d_in[0];
    const int*   ei    = (const int*)d_in[1];
    const int*   batch = (const int*)d_in[2];
    const float* seq   = (const float*)d_in[3];
    const float* Wg    = (const float*)d_in[4];
    const float* attS  = (const float*)d_in[5];
    const float* attD  = (const float*)d_in[6];
    const float* bg    = (const float*)d_in[7];
    const float* W2    = (const float*)d_in[8];
    const float* b2    = (const float*)d_in[9];
    const float* W3    = (const float*)d_in[10];
    const float* b3    = (const float*)d_in[11];
    const float* c1w   = (const float*)d_in[12];
    const float* c1bb  = (const float*)d_in[13];
    const float* c2w   = (const float*)d_in[14];
    const float* c2bb  = (const float*)d_in[15];
    const float* bn1g  = (const float*)d_in[16];
    const float* bn1b  = (const float*)d_in[17];
    const float* bn1m  = (const float*)d_in[18];
    const float* bn1v  = (const float*)d_in[19];
    const float* bn2g  = (const float*)d_in[20];
    const float* bn2b  = (const float*)d_in[21];
    const float* bn2m  = (const float*)d_in[22];
    const float* bn2v  = (const float*)d_in[23];
    const float* fcW   = (const float*)d_in[24];
    const float* fcb   = (const float*)d_in[25];
    const float* fusW  = (const float*)d_in[26];
    const float* fusb  = (const float*)d_in[27];
    const float* cls1W = (const float*)d_in[28];
    const float* cls1b = (const float*)d_in[29];
    const float* cls3W = (const float*)d_in[30];
    const float* cls3b = (const float*)d_in[31];

    // ---- workspace arena ----
    char* wsb = (char*)d_ws;
    const size_t N = NND;
    float*    M      = (float*)wsb;                                  // 80
    float*    scv    = M + 80;                                       // 256
    float*    a_d    = scv + 256;                                    // N*4 f32
    u16*      rec    = (u16*)(a_d + N * 4);                          // N*16 u16 (32B/node)
    float*    dinv   = (float*)(rec + N * 16);                       // N
    float*    pooled = dinv + N;                                     // B*128 } zero block
    float*    cnt    = pooled + (size_t)NB * 128;                    // B     }
    unsigned* bktCur = (unsigned*)(cnt + NB);                        // 256
    unsigned* rowptr = bktCur + 256;                                 // N
    u16*      degA   = (u16*)(rowptr + N);                           // N u16 (+pad)
    u16*      w2t    = degA + N + 8;                                 // 8192 u16
    u16*      w3t    = w2t + 8192;                                   // 8192 u16
    u16*      wgt    = w3t + 8192;                                   // 8192 u16
    u16*      w1p    = wgt + 8192;                                   // 6144 u16
    u16*      w2c    = w1p + 6144;                                   // 12288 u16
    unsigned* staging= (unsigned*)(w2c + 12288);                     // NBUCK*BCAP u32 (9.6MB)
    unsigned* csr    = staging + (size_t)NBUCK * BCAP;               // NBUCK*BCAP u32 (9.6MB)
    u16*      zb     = (u16*)(csr + (size_t)NBUCK * BCAP);           // N*36 bf16 (+pad)
    u16*      h2b    = zb + N * 36 + 16;                             // N*64 bf16 (2 planes)
    u16*      g2b    = h2b + N * 64;                                 // N*64 bf16 (2 planes)
    u16*      agg3b  = g2b + N * 64;                                 // N*64 bf16 (2 planes)
    float*    sfc    = (float*)(agg3b + N * 64);                     // B*64

    size_t zero_bytes = ((size_t)NB * 128 + NB) * 4;
    hipMemsetAsync(pooled, 0, zero_bytes, stream);

    k_matt<<<1, 128, 0, stream>>>(Wg, attS, attD, c1bb, c2bb, bn1g, bn1b, bn1m, bn1v,
                                  bn2g, bn2b, bn2m, bn2v, M, scv);
    k_w2t<<<32, 256, 0, stream>>>(W2, W3, Wg, c1w, c2w, w2t, w3t, wgt, w1p, w2c, bktCur);
    k_att<<<(NND + 255) / 256, 256, 0, stream>>>(x, M, rec, a_d);
    k_bin<<<BIN_NBLK, 256, 0, stream>>>(ei, bktCur, staging);
    k_place<<<NBUCK, 512, 0, stream>>>(bktCur, staging, csr, rowptr, degA, dinv);
    k_gat_g<<<NND / 4, 256, 0, stream>>>(rowptr, degA, csr, rec, a_d, zb);
    k_fused_h2<<<(NND + 63) / 64, 256, 0, stream>>>(zb, wgt, bg, w2t, dinv, h2b);
    // GCN layer 1: two sequential half-channel passes (L2 working-set split)
    k_gcn_gp<1><<<NND / 4, 256, 0, stream>>>(rowptr, degA, csr, dinv,
                                             h2b, b2, g2b);
    k_gcn_gp<1><<<NND / 4, 256, 0, stream>>>(rowptr, degA, csr, dinv,
                                             h2b + N * 32, b2 + 32, g2b + N * 32);
    // GCN layer 2
    k_gcn_gp<0><<<NND / 4, 256, 0, stream>>>(rowptr, degA, csr, dinv,
                                             g2b, b2, agg3b);
    k_gcn_gp<0><<<NND / 4, 256, 0, stream>>>(rowptr, degA, csr, dinv,
                                             g2b + N * 32, b2, agg3b + N * 32);
    k_gcn2_pool<<<(NND + 63) / 64, 256, 0, stream>>>(agg3b, w3t, b3, batch, pooled, cnt);
    k_seq<<<NB, 256, 0, stream>>>(seq, w1p, w2c, scv, fcW, fcb, sfc);
    k_final<<<NB, 128, 0, stream>>>(pooled, cnt, sfc, fusW, fusb, cls1W, cls1b,
                                    cls3W, cls3b, (float*)d_out);
}

// Round 19
// 408.266 us; speedup vs baseline: 1.1237x; 1.1237x over previous
//
#include <hip/hip_runtime.h>

#define NND 100000
#define NED 1600000
#define NB  1024
#define FEAT 9
#define HC 128
#define NBUCK ((NND + 511) / 512)            // 196 buckets of 512 nodes
#define BCAP 12288u                          // fixed bucket capacity (mean 8192, +45 sigma)
#define BINCHUNK 4096
#define BIN_NBLK ((NED + BINCHUNK - 1) / BINCHUNK)  // 391

typedef unsigned short u16;

__device__ __forceinline__ void atomAdd(float* p, float v) {
    __hip_atomic_fetch_add(p, v, __ATOMIC_RELAXED, __HIP_MEMORY_SCOPE_AGENT);
}
__device__ __forceinline__ unsigned atomAddU(unsigned* p, unsigned v) {
    return __hip_atomic_fetch_add(p, v, __ATOMIC_RELAXED, __HIP_MEMORY_SCOPE_AGENT);
}
__device__ __forceinline__ float leaky(float v, float s) { return v >= 0.f ? v : s * v; }
__device__ __forceinline__ float bf2f(u16 u) {
    union { unsigned i; float f; } x; x.i = ((unsigned)u) << 16; return x.f;
}
__device__ __forceinline__ u16 f2bf(float f) {
    union { float f; unsigned i; } x; x.f = f;
    return (u16)((x.i + 0x7fffu + ((x.i >> 16) & 1u)) >> 16);
}
__device__ __forceinline__ float bflo(unsigned u) {
    union { unsigned i; float f; } x; x.i = u << 16; return x.f;
}
__device__ __forceinline__ float bfhi(unsigned u) {
    union { unsigned i; float f; } x; x.i = u & 0xffff0000u; return x.f;
}

typedef __attribute__((ext_vector_type(8))) short bfrag;
typedef __attribute__((ext_vector_type(4))) float ffrag;

// ---- K1: M tables + BN scale/offset folding (one block, 128 thr) ----
__global__ void k_matt(const float* __restrict__ Wg, const float* __restrict__ attS,
                       const float* __restrict__ attD,
                       const float* __restrict__ c1b, const float* __restrict__ c2b,
                       const float* __restrict__ g1n, const float* __restrict__ b1n,
                       const float* __restrict__ m1n, const float* __restrict__ v1n,
                       const float* __restrict__ g2n, const float* __restrict__ b2n,
                       const float* __restrict__ m2n, const float* __restrict__ v2n,
                       float* __restrict__ M, float* __restrict__ scv) {
    int t = threadIdx.x;  // 128
    if (t < 64) {
        float s1 = g1n[t] * rsqrtf(v1n[t] + 1e-5f);
        float s2 = g2n[t] * rsqrtf(v2n[t] + 1e-5f);
        scv[t] = s1;
        scv[64 + t] = (c1b[t] - m1n[t]) * s1 + b1n[t];
        scv[128 + t] = s2;
        scv[192 + t] = (c2b[t] - m2n[t]) * s2 + b2n[t];
    }
    if (t >= 72) return;
    int d = t >= 36 ? 1 : 0;
    int q = t - 36 * d;
    int f = q >> 2, h = q & 3;
    const float* av = d ? attD : attS;
    float s = 0.f;
#pragma unroll
    for (int c = 0; c < 32; ++c) s += Wg[f * HC + h * 32 + c] * av[h * 32 + c];
    M[d * 36 + q] = s;
}

// ---- K1b: weight tables; w1p padded [64][96]; w2c [64][192]; init bktCur ----
__global__ void k_w2t(const float* __restrict__ W2, const float* __restrict__ W3,
                      const float* __restrict__ Wg,
                      const float* __restrict__ c1w, const float* __restrict__ c2w,
                      u16* __restrict__ w2t, u16* __restrict__ w3t,
                      u16* __restrict__ wgt, u16* __restrict__ w1p,
                      u16* __restrict__ w2c, unsigned* __restrict__ bktCur) {
    int i = blockIdx.x * 256 + threadIdx.x;  // 8192
    int n = i >> 7, k = i & 127;
    w2t[i] = f2bf(W2[k * 64 + n]);
    int n3 = i >> 6, k3 = i & 63;
    w3t[i] = f2bf(W3[k3 * 128 + n3]);
    int col = i >> 6, kk = i & 63;
    int f = kk - 9 * (col >> 5);
    wgt[i] = (f >= 0 && f < 9) ? f2bf(Wg[f * 128 + col]) : (u16)0;
    if (i < 6144) {
        int o = i / 96, kw = i - o * 96;
        w1p[i] = (kw < 90) ? f2bf(c1w[o * 90 + kw]) : (u16)0;
    }
    for (int j = i; j < 12288; j += 8192) w2c[j] = f2bf(c2w[j]);
    if (i < NBUCK) bktCur[i] = (unsigned)i * BCAP;
}

// ---- K2: per-node 32B bf16 record rec = {x[9], pad[3], a_s[4]} + a_d f32 ----
__global__ void k_att(const float* __restrict__ x, const float* __restrict__ M,
                      u16* __restrict__ rec, float* __restrict__ a_d) {
    __shared__ float Ms[36], Md[36];
    int t = threadIdx.x;  // 256
    if (t < 36) Ms[t] = M[t];
    else if (t < 72) Md[t - 36] = M[t];
    __syncthreads();
    int n = blockIdx.x * 256 + t;
    if (n >= NND) return;
    float xv[FEAT];
#pragma unroll
    for (int f = 0; f < FEAT; ++f) xv[f] = x[n * FEAT + f];
    float s0 = 0, s1 = 0, s2 = 0, s3 = 0, d0 = 0, d1 = 0, d2 = 0, d3 = 0;
#pragma unroll
    for (int f = 0; f < FEAT; ++f) {
        float xf = xv[f];
        s0 += xf * Ms[f * 4 + 0]; s1 += xf * Ms[f * 4 + 1];
        s2 += xf * Ms[f * 4 + 2]; s3 += xf * Ms[f * 4 + 3];
        d0 += xf * Md[f * 4 + 0]; d1 += xf * Md[f * 4 + 1];
        d2 += xf * Md[f * 4 + 2]; d3 += xf * Md[f * 4 + 3];
    }
    u16 v[16];
#pragma unroll
    for (int f = 0; f < FEAT; ++f) v[f] = f2bf(xv[f]);
    v[9] = 0; v[10] = 0; v[11] = 0;
    v[12] = f2bf(s0); v[13] = f2bf(s1); v[14] = f2bf(s2); v[15] = f2bf(s3);
    unsigned pk[8];
#pragma unroll
    for (int i = 0; i < 8; ++i) pk[i] = (unsigned)v[2 * i] | ((unsigned)v[2 * i + 1] << 16);
    uint4* rp = (uint4*)(rec + (size_t)n * 16);
    rp[0] = make_uint4(pk[0], pk[1], pk[2], pk[3]);
    rp[1] = make_uint4(pk[4], pk[5], pk[6], pk[7]);
    ((float4*)a_d)[n] = make_float4(d0, d1, d2, d3);
}

// ---- K5: bin edges into fixed-capacity bucket staging, packed (dstLocal<<17)|src ----
__global__ __launch_bounds__(256) void k_bin(const int* __restrict__ ei,
                                             unsigned* __restrict__ bktCursor,
                                             unsigned* __restrict__ staging) {
    __shared__ unsigned hist[NBUCK];
    __shared__ unsigned gbase[NBUCK];
    int t = threadIdx.x;
    if (t < NBUCK) hist[t] = 0;
    __syncthreads();
    int base = blockIdx.x * BINCHUNK;
    int lim = NED - base;
    int srcv[16], dstv[16];
#pragma unroll
    for (int k = 0; k < 16; ++k) {
        int i = t + k * 256;
        if (i < lim) {
            srcv[k] = ei[base + i];
            dstv[k] = ei[NED + base + i];
            atomicAdd(&hist[dstv[k] >> 9], 1u);
        } else dstv[k] = -1;
    }
    __syncthreads();
    if (t < NBUCK) {
        unsigned c = hist[t];
        gbase[t] = c ? atomAddU(&bktCursor[t], c) : 0u;
    }
    __syncthreads();
    if (t < NBUCK) hist[t] = 0;
    __syncthreads();
#pragma unroll
    for (int k = 0; k < 16; ++k) {
        if (dstv[k] >= 0) {
            int bk = dstv[k] >> 9;
            unsigned off = atomicAdd(&hist[bk], 1u);
            staging[gbase[bk] + off] = ((unsigned)(dstv[k] & 511) << 17) | (unsigned)srcv[k];
        }
    }
}

// ---- K6: per-bucket CSR build ----
__global__ __launch_bounds__(512) void k_place(const unsigned* __restrict__ bktCur,
                                               const unsigned* __restrict__ staging,
                                               unsigned* __restrict__ csr,
                                               unsigned* __restrict__ rowptr,
                                               u16* __restrict__ degA,
                                               float* __restrict__ dinv) {
    __shared__ unsigned lh[512];
    __shared__ unsigned ls[512];
    int b = blockIdx.x, t = threadIdx.x;
    unsigned lo = (unsigned)b * BCAP;
    unsigned n = bktCur[b] - lo;
    lh[t] = 0;
    __syncthreads();
    for (unsigned i = t; i < n; i += 512) atomicAdd(&lh[staging[lo + i] >> 17], 1u);
    __syncthreads();
    unsigned v = lh[t];
    ls[t] = v;
    __syncthreads();
    for (int off = 1; off < 512; off <<= 1) {
        unsigned u = (t >= off) ? ls[t - off] : 0u;
        __syncthreads();
        ls[t] += u;
        __syncthreads();
    }
    unsigned excl = ls[t] - v;
    int node = b * 512 + t;
    if (node < NND) {
        rowptr[node] = lo + excl;
        degA[node] = (u16)v;
        dinv[node] = rsqrtf((float)v + 1.f);
    }
    __syncthreads();
    lh[t] = excl;  // reuse as local cursor
    __syncthreads();
    for (unsigned i = t; i < n; i += 512) {
        unsigned p = staging[lo + i];
        unsigned pos = atomicAdd(&lh[p >> 17], 1u);
        csr[lo + pos] = p & 0x1FFFFu;
    }
}

// ---- K7: GAT aggregation, EDGE-PARALLEL: wave per node; z output bf16 ----
__global__ __launch_bounds__(256) void k_gat_g(const unsigned* __restrict__ rowptr,
                                               const u16* __restrict__ degA,
                                               const unsigned* __restrict__ csr,
                                               const u16* __restrict__ rec,
                                               const float* __restrict__ a_d,
                                               u16* __restrict__ zb) {
    int n = blockIdx.x * 4 + (threadIdx.x >> 6);  // grid NND/4 x 256 exact
    int l = threadIdx.x & 63;
    int e = l >> 2;   // 0..15 edge slot
    int h = l & 3;    // head
    unsigned e0 = rowptr[n];
    int m = (int)degA[n] + 1;  // items incl self
    float adh = a_d[n * 4 + h];
    float acc0 = 0, acc1 = 0, acc2 = 0, acc3 = 0, acc4 = 0, acc5 = 0, acc6 = 0, acc7 = 0, acc8 = 0;
    float den = 0.f;
    const uint4* recp = (const uint4*)rec;
    for (int c = 0; c < m; c += 16) {
        int idx = c + e;
        bool act = idx < m;
        int src = n;
        if (act && idx > 0) src = (int)csr[e0 + idx - 1];
        uint4 lo = recp[(size_t)src * 2];
        uint4 hi = recp[(size_t)src * 2 + 1];
        unsigned pair = (h & 2) ? hi.w : hi.z;
        float asf = (h & 1) ? bfhi(pair) : bflo(pair);
        float w = __expf(leaky(asf + adh, 0.2f));
        if (!act) w = 0.f;
        den += w;
        acc0 += w * bflo(lo.x); acc1 += w * bfhi(lo.x);
        acc2 += w * bflo(lo.y); acc3 += w * bfhi(lo.y);
        acc4 += w * bflo(lo.z); acc5 += w * bfhi(lo.z);
        acc6 += w * bflo(lo.w); acc7 += w * bfhi(lo.w);
        acc8 += w * bflo(hi.x);
    }
#pragma unroll
    for (int mask = 4; mask <= 32; mask <<= 1) {
        den  += __shfl_xor(den,  mask, 64);
        acc0 += __shfl_xor(acc0, mask, 64);
        acc1 += __shfl_xor(acc1, mask, 64);
        acc2 += __shfl_xor(acc2, mask, 64);
        acc3 += __shfl_xor(acc3, mask, 64);
        acc4 += __shfl_xor(acc4, mask, 64);
        acc5 += __shfl_xor(acc5, mask, 64);
        acc6 += __shfl_xor(acc6, mask, 64);
        acc7 += __shfl_xor(acc7, mask, 64);
        acc8 += __shfl_xor(acc8, mask, 64);
    }
    if (l < 4) {  // e==0, h=l
        float inv = 1.f / (den + 1e-16f);
        u16* zp = zb + (size_t)n * 36 + h * 9;
        zp[0] = f2bf(acc0 * inv); zp[1] = f2bf(acc1 * inv); zp[2] = f2bf(acc2 * inv);
        zp[3] = f2bf(acc3 * inv); zp[4] = f2bf(acc4 * inv); zp[5] = f2bf(acc5 * inv);
        zp[6] = f2bf(acc6 * inv); zp[7] = f2bf(acc7 * inv); zp[8] = f2bf(acc8 * inv);
    }
}

// ---- K9: MFMA g1 + MFMA h2: h2 = bf16(dinv*(leaky(zb@wgt^T+bg) @ W2)) ----
__global__ __launch_bounds__(256) void k_fused_h2(const u16* __restrict__ zb,
                                                  const u16* __restrict__ wgt,
                                                  const float* __restrict__ bgv,
                                                  const u16* __restrict__ w2t,
                                                  const float* __restrict__ dinv,
                                                  u16* __restrict__ h2) {
    __shared__ u16 zA[64 * 72];     // 9.2 KB (K padded to 64, zeroed)
    __shared__ u16 g1L[64 * 136];   // 17.4 KB
    __shared__ float bgs[HC];
    int t = threadIdx.x;
    int n0 = blockIdx.x * 64;
    int nn = NND - n0; if (nn > 64) nn = 64;
    for (int i = t; i < 64 * 36; i += 256) ((unsigned*)zA)[i] = 0u;
    if (t < HC) bgs[t] = bgv[t];
    __syncthreads();
    const unsigned* zbG = (const unsigned*)zb;  // 18 u32 per node
    for (int i = t; i < nn * 18; i += 256) {
        int r = i / 18, c = i - r * 18;
        ((unsigned*)zA)[r * 36 + c] = zbG[(size_t)(n0 + r) * 18 + c];
    }
    __syncthreads();
    int l = t & 63, wv = t >> 6;
    int mr = l & 15, quad = l >> 4;
    union U { uint4 u; bfrag v; };
    // ---- Phase 2: g1 = zA @ wgt^T (K=64) -> g1L bf16 ----
    {
        bfrag a[2];
#pragma unroll
        for (int ks = 0; ks < 2; ++ks) {
            U uu; uu.u = *(const uint4*)(zA + (wv * 16 + mr) * 72 + ks * 32 + quad * 8);
            a[ks] = uu.v;
        }
#pragma unroll
        for (int ct = 0; ct < 8; ++ct) {
            ffrag c = (ffrag){0.f, 0.f, 0.f, 0.f};
#pragma unroll
            for (int ks = 0; ks < 2; ++ks) {
                U ub; ub.u = *(const uint4*)(wgt + (ct * 16 + mr) * 64 + ks * 32 + quad * 8);
                c = __builtin_amdgcn_mfma_f32_16x16x32_bf16(a[ks], ub.v, c, 0, 0, 0);
            }
            int col = ct * 16 + mr;
            float bc = bgs[col];
#pragma unroll
            for (int r = 0; r < 4; ++r) {
                int row = wv * 16 + quad * 4 + r;
                g1L[row * 136 + col] = f2bf(leaky(c[r] + bc, 0.01f));
            }
        }
    }
    __syncthreads();
    // ---- Phase 3: h2 = g1L @ w2t ----
    {
        bfrag a[4];
#pragma unroll
        for (int ks = 0; ks < 4; ++ks) {
            U uu; uu.u = *(const uint4*)(g1L + (wv * 16 + mr) * 136 + ks * 32 + quad * 8);
            a[ks] = uu.v;
        }
        ffrag acc[4];
#pragma unroll
        for (int ct = 0; ct < 4; ++ct) acc[ct] = (ffrag){0.f, 0.f, 0.f, 0.f};
#pragma unroll
        for (int ct = 0; ct < 4; ++ct) {
#pragma unroll
            for (int ks = 0; ks < 4; ++ks) {
                U ub; ub.u = *(const uint4*)(w2t + (ct * 16 + mr) * 128 + ks * 32 + quad * 8);
                acc[ct] = __builtin_amdgcn_mfma_f32_16x16x32_bf16(a[ks], ub.v, acc[ct], 0, 0, 0);
            }
        }
        int rbase = n0 + wv * 16 + quad * 4;
        if (rbase < NND) {  // NND%4==0
            float4 d4 = *(const float4*)(dinv + rbase);
            const float dv[4] = {d4.x, d4.y, d4.z, d4.w};
#pragma unroll
            for (int ct = 0; ct < 4; ++ct)
#pragma unroll
                for (int r = 0; r < 4; ++r)
                    h2[(size_t)(rbase + r) * 64 + ct * 16 + mr] = f2bf(dv[r] * acc[ct][r]);
        }
    }
}

// ---- K10/K11: GCN aggregation, QUAD-edge ----
template <int OUTMODE>
__global__ void k_gcn_g(const unsigned* __restrict__ rowptr, const u16* __restrict__ degA,
                        const unsigned* __restrict__ csr,
                        const float* __restrict__ dinv, const u16* __restrict__ hin,
                        const float* __restrict__ bias, u16* __restrict__ hout) {
    int n = blockIdx.x * 4 + (threadIdx.x >> 6);  // grid 25000 x 256 exact
    int l = threadIdx.x & 63;
    int grp = l >> 4;
    int c = l & 15;
    unsigned e0 = rowptr[n];
    unsigned e1 = e0 + degA[n];
    const uint2* hinU = (const uint2*)hin;
    float a0 = 0, a1 = 0, a2 = 0, a3 = 0;
    if (grp == 0) {
        uint2 u = hinU[(size_t)n * 16 + c];
        a0 = bflo(u.x); a1 = bfhi(u.x); a2 = bflo(u.y); a3 = bfhi(u.y);
    }
    unsigned e = e0;
    for (; e + 8 <= e1; e += 8) {
        unsigned s0 = csr[e + grp];
        unsigned s1 = csr[e + 4 + grp];
        uint2 u0 = hinU[(size_t)s0 * 16 + c];
        uint2 u1 = hinU[(size_t)s1 * 16 + c];
        a0 += bflo(u0.x) + bflo(u1.x); a1 += bfhi(u0.x) + bfhi(u1.x);
        a2 += bflo(u0.y) + bflo(u1.y); a3 += bfhi(u0.y) + bfhi(u1.y);
    }
    for (; e + 4 <= e1; e += 4) {
        unsigned s = csr[e + grp];
        uint2 u = hinU[(size_t)s * 16 + c];
        a0 += bflo(u.x); a1 += bfhi(u.x); a2 += bflo(u.y); a3 += bfhi(u.y);
    }
    if (grp < (int)(e1 - e)) {
        unsigned s = csr[e + grp];
        uint2 u = hinU[(size_t)s * 16 + c];
        a0 += bflo(u.x); a1 += bfhi(u.x); a2 += bflo(u.y); a3 += bfhi(u.y);
    }
#pragma unroll
    for (int mask = 16; mask <= 32; mask <<= 1) {
        a0 += __shfl_xor(a0, mask, 64);
        a1 += __shfl_xor(a1, mask, 64);
        a2 += __shfl_xor(a2, mask, 64);
        a3 += __shfl_xor(a3, mask, 64);
    }
    if (grp == 0) {
        float dn = dinv[n];
        float o0 = dn * a0, o1 = dn * a1, o2 = dn * a2, o3 = dn * a3;
        if (OUTMODE == 1) {
            o0 = leaky(o0 + bias[4 * c],     0.01f) * dn;
            o1 = leaky(o1 + bias[4 * c + 1], 0.01f) * dn;
            o2 = leaky(o2 + bias[4 * c + 2], 0.01f) * dn;
            o3 = leaky(o3 + bias[4 * c + 3], 0.01f) * dn;
        }
        uint2 pk;
        pk.x = (unsigned)f2bf(o0) | ((unsigned)f2bf(o1) << 16);
        pk.y = (unsigned)f2bf(o2) | ((unsigned)f2bf(o3) << 16);
        ((uint2*)hout)[(size_t)n * 16 + c] = pk;
    }
}

// ---- K12: MFMA GEMM + fused mean-pool ----
__global__ __launch_bounds__(256) void k_gcn2_pool(const u16* __restrict__ agg3,
                                                   const u16* __restrict__ w3t,
                                                   const float* __restrict__ b3,
                                                   const int* __restrict__ batch,
                                                   float* __restrict__ pooled,
                                                   float* __restrict__ cnt) {
    __shared__ u16 rows[64 * 72];
    __shared__ int bts[64];
    __shared__ float b3s[128];
    int t = threadIdx.x;
    int n0 = blockIdx.x * 64;
    int nn = NND - n0; if (nn > 64) nn = 64;
    const uint4* src = (const uint4*)(agg3 + (size_t)n0 * 64);  // 8 uint4 per row
    for (int i = t; i < 512; i += 256) {
        int r = i >> 3, c8 = i & 7;
        uint4 v = (r < nn) ? src[i] : make_uint4(0u, 0u, 0u, 0u);
        *(uint4*)(rows + r * 72 + c8 * 8) = v;
    }
    if (t < 64) bts[t] = (t < nn) ? batch[n0 + t] : -1;
    if (t < 128) b3s[t] = b3[t];
    __syncthreads();
    int l = t & 63, wv = t >> 6;
    int mr = l & 15, quad = l >> 4;
    union U { uint4 u; bfrag v; };
    bfrag a[2];
#pragma unroll
    for (int ks = 0; ks < 2; ++ks) {
        U uu; uu.u = *(const uint4*)(rows + (wv * 16 + mr) * 72 + ks * 32 + quad * 8);
        a[ks] = uu.v;
    }
    ffrag acc[8];
#pragma unroll
    for (int ct = 0; ct < 8; ++ct) acc[ct] = (ffrag){0.f, 0.f, 0.f, 0.f};
#pragma unroll
    for (int ct = 0; ct < 8; ++ct) {
#pragma unroll
        for (int ks = 0; ks < 2; ++ks) {
            U ub; ub.u = *(const uint4*)(w3t + (ct * 16 + mr) * 64 + ks * 32 + quad * 8);
            acc[ct] = __builtin_amdgcn_mfma_f32_16x16x32_bf16(a[ks], ub.v, acc[ct], 0, 0, 0);
        }
    }
    int rl = wv * 16 + quad * 4;
    int ub = bts[wv * 16];
    bool uni = (ub == bts[wv * 16 + 15]);
#pragma unroll
    for (int ct = 0; ct < 8; ++ct) {
        int col = ct * 16 + mr;
        float bc = b3s[col];
        float g0 = leaky(acc[ct][0] + bc, 0.01f);
        float g1 = leaky(acc[ct][1] + bc, 0.01f);
        float g2 = leaky(acc[ct][2] + bc, 0.01f);
        float g3 = leaky(acc[ct][3] + bc, 0.01f);
        if (uni) {
            float s = g0 + g1 + g2 + g3;
            s += __shfl_xor(s, 16, 64);
            s += __shfl_xor(s, 32, 64);
            if (quad == 0 && ub >= 0) atomAdd(&pooled[ub * 128 + col], s);
        } else {
            float gr[4] = {g0, g1, g2, g3};
            int curb = bts[rl];
            float s = 0.f;
#pragma unroll
            for (int r = 0; r < 4; ++r) {
                int b = bts[rl + r];
                if (b != curb) {
                    if (curb >= 0) atomAdd(&pooled[curb * 128 + col], s);
                    s = 0.f; curb = b;
                }
                s += gr[r];
            }
            if (curb >= 0) atomAdd(&pooled[curb * 128 + col], s);
        }
    }
    if (t < nn) {
        int b = bts[t];
        if (t == 0 || bts[t - 1] != b) {
            int len = 1;
            for (int j = t + 1; j < nn && bts[j] == b; ++j) ++len;
            atomAdd(&cnt[b], (float)len);
        }
    }
}

// ---- K14: sequence branch via MFMA im2col convs -> sfc [B,64] ----
__global__ __launch_bounds__(256) void k_seq(const float* __restrict__ seq,
                      const u16* __restrict__ w1p, const u16* __restrict__ w2c,
                      const float* __restrict__ scv,
                      const float* __restrict__ fcW, const float* __restrict__ fcb,
                      float* __restrict__ sfc) {
    __shared__ float xs[600];
    __shared__ u16 A1[32 * 104];    // 6.7 KB, K padded 90->96
    __shared__ u16 y1s[64 * 20];    // [ch][l] bf16
    __shared__ u16 A2[16 * 200];    // 6.4 KB, K=192
    __shared__ float y2s[64 * 16];  // [ch][l] f32
    __shared__ float red[4][64];
    int t = threadIdx.x;  // 256
    int b = blockIdx.x;
    for (int i = t; i < 600; i += 256) xs[i] = seq[b * 600 + i];
    for (int i = t; i < 1664; i += 256) ((unsigned*)A1)[i] = 0u;
    for (int i = t; i < 1600; i += 256) ((unsigned*)A2)[i] = 0u;
    __syncthreads();
    for (int i = t; i < 18 * 90; i += 256) {
        int l = i / 90, k = i - l * 90;
        int ch = k / 3, kk = k - ch * 3;
        A1[l * 104 + k] = f2bf(xs[ch * 20 + l + kk]);
    }
    __syncthreads();
    int l = t & 63, wv = t >> 6;
    int mr = l & 15, quad = l >> 4;
    union U { uint4 u; bfrag v; };
    for (int j = wv; j < 8; j += 4) {
        int rt = j >> 2, ct = j & 3;
        ffrag c = (ffrag){0.f, 0.f, 0.f, 0.f};
#pragma unroll
        for (int ks = 0; ks < 3; ++ks) {
            U ua; ua.u = *(const uint4*)(A1 + (rt * 16 + mr) * 104 + ks * 32 + quad * 8);
            U ub; ub.u = *(const uint4*)(w1p + (ct * 16 + mr) * 96 + ks * 32 + quad * 8);
            c = __builtin_amdgcn_mfma_f32_16x16x32_bf16(ua.v, ub.v, c, 0, 0, 0);
        }
        int col = ct * 16 + mr;
        float s1 = scv[col], o1 = scv[64 + col];
#pragma unroll
        for (int r = 0; r < 4; ++r) {
            int row = rt * 16 + quad * 4 + r;
            if (row < 18) y1s[col * 20 + row] = f2bf(leaky(c[r] * s1 + o1, 0.01f));
        }
    }
    __syncthreads();
    for (int i = t; i < 16 * 192; i += 256) {
        int ll = i / 192, k = i - ll * 192;
        int ch = k / 3, kk = k - ch * 3;
        A2[ll * 200 + k] = y1s[ch * 20 + ll + kk];
    }
    __syncthreads();
    {
        int ct = wv;
        ffrag c = (ffrag){0.f, 0.f, 0.f, 0.f};
#pragma unroll
        for (int ks = 0; ks < 6; ++ks) {
            U ua; ua.u = *(const uint4*)(A2 + mr * 200 + ks * 32 + quad * 8);
            U ub; ub.u = *(const uint4*)(w2c + (ct * 16 + mr) * 192 + ks * 32 + quad * 8);
            c = __builtin_amdgcn_mfma_f32_16x16x32_bf16(ua.v, ub.v, c, 0, 0, 0);
        }
        int col = ct * 16 + mr;
        float s2 = scv[128 + col], o2 = scv[192 + col];
#pragma unroll
        for (int r = 0; r < 4; ++r) {
            int row = quad * 4 + r;
            y2s[col * 16 + row] = leaky(c[r] * s2 + o2, 0.01f);
        }
    }
    __syncthreads();
    {
        int o = t & 63, part = t >> 6;
        float acc = 0.f;
        for (int j = part * 256; j < part * 256 + 256; ++j)
            acc += y2s[j] * fcW[j * 64 + o];
        red[part][o] = acc;
    }
    __syncthreads();
    if (t < 64) sfc[b * 64 + t] = red[0][t] + red[1][t] + red[2][t] + red[3][t] + fcb[t];
}

// ---- K15: fusion + classifier -> out [B,1] f32 ----
__global__ void k_final(const float* __restrict__ pooled, const float* __restrict__ cnt,
                        const float* __restrict__ sfc,
                        const float* __restrict__ fusW, const float* __restrict__ fusb,
                        const float* __restrict__ c1W, const float* __restrict__ c1b,
                        const float* __restrict__ c3W, const float* __restrict__ c3b,
                        float* __restrict__ out) {
    __shared__ float comb[192];
    __shared__ float t1[128];
    int t = threadIdx.x;  // 128
    int b = blockIdx.x;
    float invc = 1.f / fmaxf(cnt[b], 1.f);
    comb[t] = pooled[b * 128 + t] * invc;
    if (t < 64) comb[128 + t] = sfc[b * 64 + t];
    __syncthreads();
    float acc = fusb[t];
    for (int k = 0; k < 192; ++k) acc += comb[k] * fusW[k * 128 + t];
    t1[t] = leaky(acc, 0.01f);
    __syncthreads();
    if (t < 64) {
        float a2 = c1b[t];
        for (int k = 0; k < 128; ++k) a2 += t1[k] * c1W[k * 64 + t];
        a2 = leaky(a2, 0.01f);
        float p = a2 * c3W[t];
#pragma unroll
        for (int off = 32; off; off >>= 1) p += __shfl_xor(p, off, 64);
        if (t == 0) out[b] = p + c3b[0];
    }
}

extern "C" void kernel_launch(void* const* d_in, const int* in_sizes, int n_in,
                              void* d_out, int out_size, void* d_ws, size_t ws_size,
                              hipStream_t stream) {
    const float* x     = (const float*)d_in[0];
    const int*   ei    = (const int*)d_in[1];
    const int*   batch = (const int*)d_in[2];
    const float* seq   = (const float*)d_in[3];
    const float* Wg    = (const float*)d_in[4];
    const float* attS  = (const float*)d_in[5];
    const float* attD  = (const float*)d_in[6];
    const float* bg    = (const float*)d_in[7];
    const float* W2    = (const float*)d_in[8];
    const float* b2    = (const float*)d_in[9];
    const float* W3    = (const float*)d_in[10];
    const float* b3    = (const float*)d_in[11];
    const float* c1w   = (const float*)d_in[12];
    const float* c1bb  = (const float*)d_in[13];
    const float* c2w   = (const float*)d_in[14];
    const float* c2bb  = (const float*)d_in[15];
    const float* bn1g  = (const float*)d_in[16];
    const float* bn1b  = (const float*)d_in[17];
    const float* bn1m  = (const float*)d_in[18];
    const float* bn1v  = (const float*)d_in[19];
    const float* bn2g  = (const float*)d_in[20];
    const float* bn2b  = (const float*)d_in[21];
    const float* bn2m  = (const float*)d_in[22];
    const float* bn2v  = (const float*)d_in[23];
    const float* fcW   = (const float*)d_in[24];
    const float* fcb   = (const float*)d_in[25];
    const float* fusW  = (const float*)d_in[26];
    const float* fusb  = (const float*)d_in[27];
    const float* cls1W = (const float*)d_in[28];
    const float* cls1b = (const float*)d_in[29];
    const float* cls3W = (const float*)d_in[30];
    const float* cls3b = (const float*)d_in[31];

    // ---- workspace arena ----
    char* wsb = (char*)d_ws;
    const size_t N = NND;
    float*    M      = (float*)wsb;                                  // 80
    float*    scv    = M + 80;                                       // 256
    float*    a_d    = scv + 256;                                    // N*4 f32
    u16*      rec    = (u16*)(a_d + N * 4);                          // N*16 u16 (32B/node)
    float*    dinv   = (float*)(rec + N * 16);                       // N
    float*    pooled = dinv + N;                                     // B*128 } zero block
    float*    cnt    = pooled + (size_t)NB * 128;                    // B     }
    unsigned* bktCur = (unsigned*)(cnt + NB);                        // 256
    unsigned* rowptr = bktCur + 256;                                 // N
    u16*      degA   = (u16*)(rowptr + N);                           // N u16 (+pad)
    u16*      w2t    = degA + N + 8;                                 // 8192 u16
    u16*      w3t    = w2t + 8192;                                   // 8192 u16
    u16*      wgt    = w3t + 8192;                                   // 8192 u16
    u16*      w1p    = wgt + 8192;                                   // 6144 u16
    u16*      w2c    = w1p + 6144;                                   // 12288 u16
    unsigned* staging= (unsigned*)(w2c + 12288);                     // NBUCK*BCAP u32 (9.6MB)
    unsigned* csr    = staging + (size_t)NBUCK * BCAP;               // NBUCK*BCAP u32 (9.6MB)
    u16*      zb     = (u16*)(csr + (size_t)NBUCK * BCAP);           // N*36 bf16 (+pad)
    u16*      h2b    = zb + N * 36 + 16;                             // N*64 bf16
    u16*      g2b    = h2b + N * 64;                                 // N*64 bf16
    u16*      agg3b  = g2b + N * 64;                                 // N*64 bf16
    float*    sfc    = (float*)(agg3b + N * 64);                     // B*64

    size_t zero_bytes = ((size_t)NB * 128 + NB) * 4;
    hipMemsetAsync(pooled, 0, zero_bytes, stream);

    k_matt<<<1, 128, 0, stream>>>(Wg, attS, attD, c1bb, c2bb, bn1g, bn1b, bn1m, bn1v,
                                  bn2g, bn2b, bn2m, bn2v, M, scv);
    k_w2t<<<32, 256, 0, stream>>>(W2, W3, Wg, c1w, c2w, w2t, w3t, wgt, w1p, w2c, bktCur);
    k_att<<<(NND + 255) / 256, 256, 0, stream>>>(x, M, rec, a_d);
    k_bin<<<BIN_NBLK, 256, 0, stream>>>(ei, bktCur, staging);
    k_place<<<NBUCK, 512, 0, stream>>>(bktCur, staging, csr, rowptr, degA, dinv);
    k_gat_g<<<NND / 4, 256, 0, stream>>>(rowptr, degA, csr, rec, a_d, zb);
    k_fused_h2<<<(NND + 63) / 64, 256, 0, stream>>>(zb, wgt, bg, w2t, dinv, h2b);
    k_gcn_g<1><<<NND / 4, 256, 0, stream>>>(rowptr, degA, csr, dinv, h2b, b2, g2b);
    k_gcn_g<0><<<NND / 4, 256, 0, stream>>>(rowptr, degA, csr, dinv, g2b, b2, agg3b);
    k_gcn2_pool<<<(NND + 63) / 64, 256, 0, stream>>>(agg3b, w3t, b3, batch, pooled, cnt);
    k_seq<<<NB, 256, 0, stream>>>(seq, w1p, w2c, scv, fcW, fcb, sfc);
    k_final<<<NB, 128, 0, stream>>>(pooled, cnt, sfc, fusW, fusb, cls1W, cls1b,
                                    cls3W, cls3b, (float*)d_out);
}